// Round 5
// baseline (205.378 us; speedup 1.0000x reference)
//
#include <hip/hip_runtime.h>
#include <hip/hip_bf16.h>

typedef __attribute__((ext_vector_type(4))) float        f32x4;
typedef __attribute__((ext_vector_type(8))) short        s16x8;
typedef __attribute__((ext_vector_type(4))) unsigned int u32x4;
typedef __attribute__((ext_vector_type(2))) unsigned int u32x2;

#define Bb 8
#define Tt 1024
#define Ss 1024
#define Dd 2048
#define BM 128
#define BN 128
#define BK 64   // K-slab per barrier: 32 iters, 32 MFMA/wave/iter

// round-half-up f32 -> bf16, packed pair. Inputs are finite N(0,1); no NaN/Inf path.
__device__ __forceinline__ unsigned pack2_bf16(float f0, float f1) {
  unsigned u0 = __builtin_bit_cast(unsigned, f0) + 0x8000u;
  unsigned u1 = __builtin_bit_cast(unsigned, f1) + 0x8000u;
  return (u0 >> 16) | (u1 & 0xffff0000u);
}

// async global->LDS DMA, 16B/lane. LDS dest = wave-uniform base + lane*16.
__device__ __forceinline__ void gld_lds16(const void* g, void* l) {
  __builtin_amdgcn_global_load_lds(
      (__attribute__((address_space(1))) void*)(void*)(g),
      (__attribute__((address_space(3))) void*)l, 16, 0, 0);
}

// ---------------- Pass 1: fp32 -> bf16 convert + row inv-norms ----------------
// One row per wave, phase-split: 8 loads all in flight, then pack, then 4x16B stores.
// Each lane owns 8 contiguous f32 (two adjacent f32x4) -> one contiguous 16B bf16 store.
__global__ __launch_bounds__(256, 8)
void convert_kernel(const float* __restrict__ sup, const float* __restrict__ xh,
                    unsigned* __restrict__ abf, unsigned* __restrict__ bbf,
                    float* __restrict__ invA, float* __restrict__ invB)
{
  const int wave = threadIdx.x >> 6, lane = threadIdx.x & 63;
  const int rowg = blockIdx.x * 4 + wave;          // 0..16383
  const float* src; unsigned* dst; float* inv; int row;
  if (rowg < 8192) { row = rowg;         src = xh;  dst = abf; inv = invA; }
  else             { row = rowg - 8192;  src = sup; dst = bbf; inv = invB; }

  const f32x4* s = (const f32x4*)(src + (size_t)row * Dd);
  f32x4 va[4], vb[4];
  #pragma unroll
  for (int j = 0; j < 4; ++j) {        // all 8 loads issued before any use
    va[j] = s[j * 128 + lane * 2];
    vb[j] = s[j * 128 + lane * 2 + 1];
  }

  float sq = 0.0f;
  u32x4 o[4];
  #pragma unroll
  for (int j = 0; j < 4; ++j) {
    f32x4 a = va[j], b = vb[j];
    sq = fmaf(a[0], a[0], fmaf(a[1], a[1], fmaf(a[2], a[2], fmaf(a[3], a[3], sq))));
    sq = fmaf(b[0], b[0], fmaf(b[1], b[1], fmaf(b[2], b[2], fmaf(b[3], b[3], sq))));
    o[j] = (u32x4){pack2_bf16(a[0], a[1]), pack2_bf16(a[2], a[3]),
                   pack2_bf16(b[0], b[1]), pack2_bf16(b[2], b[3])};
  }

  u32x4* d = (u32x4*)(dst + (size_t)row * (Dd / 2));
  #pragma unroll
  for (int j = 0; j < 4; ++j) d[j * 64 + lane] = o[j];

  #pragma unroll
  for (int m = 32; m; m >>= 1) sq += __shfl_xor(sq, m, 64);
  if (lane == 0) inv[row] = 1.0f / sqrtf(sq);
}

// ---------------- Pass 2: bf16 GEMM, DMA staging, BK=64 ----------------
// LDS tiles 128x64 bf16 (128B rows, 8 chunks of 16B).
// XOR swizzle: LDS[r][p] = G[r][p ^ (r&7)]; read chunk c at p = c ^ (r&7).
__global__ __launch_bounds__(256, 2)
void gemm_kernel(const short* __restrict__ abf, const short* __restrict__ bbf,
                 const float* __restrict__ invA, const float* __restrict__ invB,
                 float* __restrict__ out)
{
  __shared__ short As[BM * BK];   // 16 KB
  __shared__ short Bs[BN * BK];   // 16 KB

  const int bid  = blockIdx.x;
  const int b    = bid >> 6;
  const int tile = bid & 63;
  const int tm   = tile >> 3;
  const int tn   = tile & 7;

  const int t = threadIdx.x, wave = t >> 6, lane = t & 63;

  // --- staging: wave covers rows [wave*32, wave*32+32), 4 DMA instrs per operand.
  const int srow = lane >> 3;
  const int cph  = lane & 7;
  const int r0   = wave * 32;

  const size_t aRow = (size_t)(b * Tt + tm * BM);
  const size_t bRow = (size_t)(b * Ss + tn * BN);
  const short *gA0, *gA1, *gA2, *gA3, *gB0, *gB1, *gB2, *gB3;
  {
    int r;
    r = r0 + 0 * 8 + srow; gA0 = abf + (aRow + r) * Dd + (cph ^ (r & 7)) * 8;
                           gB0 = bbf + (bRow + r) * Dd + (cph ^ (r & 7)) * 8;
    r = r0 + 1 * 8 + srow; gA1 = abf + (aRow + r) * Dd + (cph ^ (r & 7)) * 8;
                           gB1 = bbf + (bRow + r) * Dd + (cph ^ (r & 7)) * 8;
    r = r0 + 2 * 8 + srow; gA2 = abf + (aRow + r) * Dd + (cph ^ (r & 7)) * 8;
                           gB2 = bbf + (bRow + r) * Dd + (cph ^ (r & 7)) * 8;
    r = r0 + 3 * 8 + srow; gA3 = abf + (aRow + r) * Dd + (cph ^ (r & 7)) * 8;
                           gB3 = bbf + (bRow + r) * Dd + (cph ^ (r & 7)) * 8;
  }
  short* lA0 = As + (r0 + 0)  * BK;  // wave-uniform bases; HW adds lane*16B
  short* lA1 = As + (r0 + 8)  * BK;
  short* lA2 = As + (r0 + 16) * BK;
  short* lA3 = As + (r0 + 24) * BK;
  short* lB0 = Bs + (r0 + 0)  * BK;
  short* lB1 = Bs + (r0 + 8)  * BK;
  short* lB2 = Bs + (r0 + 16) * BK;
  short* lB3 = Bs + (r0 + 24) * BK;

  // --- compute setup
  const int wm = (wave >> 1) << 6;
  const int wn = (wave & 1) << 6;
  const int lm = lane & 15;
  const int kq = lane >> 4;

  f32x4 acc[4][4];
  #pragma unroll
  for (int i = 0; i < 4; ++i)
    #pragma unroll
    for (int j = 0; j < 4; ++j)
      acc[i][j] = (f32x4)0.0f;

  for (int k0 = 0; k0 < Dd; k0 += BK) {
    __syncthreads();                  // previous slab's frag reads done
    gld_lds16(gA0, lA0); gld_lds16(gA1, lA1); gld_lds16(gA2, lA2); gld_lds16(gA3, lA3);
    gld_lds16(gB0, lB0); gld_lds16(gB1, lB1); gld_lds16(gB2, lB2); gld_lds16(gB3, lB3);
    gA0 += BK; gA1 += BK; gA2 += BK; gA3 += BK;
    gB0 += BK; gB1 += BK; gB2 += BK; gB3 += BK;
    __syncthreads();                  // DMA landed

    #pragma unroll
    for (int ks = 0; ks < 2; ++ks) {
      const int pchunk = ((ks * 4 + kq) ^ (lm & 7)) * 8;   // swizzled 16B chunk, in shorts
      s16x8 af[4], bfr[4];
      #pragma unroll
      for (int i = 0; i < 4; ++i) {
        af[i]  = *(const s16x8*)(As + (wm + i * 16 + lm) * BK + pchunk);
        bfr[i] = *(const s16x8*)(Bs + (wn + i * 16 + lm) * BK + pchunk);
      }
      #pragma unroll
      for (int mi = 0; mi < 4; ++mi)
        #pragma unroll
        for (int ni = 0; ni < 4; ++ni)
          acc[mi][ni] = __builtin_amdgcn_mfma_f32_16x16x32_bf16(af[mi], bfr[ni], acc[mi][ni], 0, 0, 0);
    }
  }

  // --- epilogue: scale by 1/||x|| * 1/||s|| (eps guard vacuous: norms ~45)
  const float* iA = invA + b * Tt + tm * BM;
  const float* iB = invB + b * Ss + tn * BN;
  float* outb = out + (size_t)(b * Tt + tm * BM) * Ss + tn * BN;
  const int m0 = wm + kq * 4;
  const int n0 = wn + lm;
  #pragma unroll
  for (int mi = 0; mi < 4; ++mi) {
    #pragma unroll
    for (int r = 0; r < 4; ++r) {
      const int mrow = m0 + mi * 16 + r;
      const float ia = iA[mrow];
      float* orow = outb + (size_t)mrow * Ss;
      #pragma unroll
      for (int ni = 0; ni < 4; ++ni) {
        const int ncol = n0 + ni * 16;
        orow[ncol] = acc[mi][ni][r] * (ia * iB[ncol]);
      }
    }
  }
}

// ---------------- Fallback: round-1 fused kernel (used only if ws too small) ----------------
#define LDKF 40
#define BKF 32
__global__ __launch_bounds__(256, 2)
void paircos_kernel(const float* __restrict__ sup, const float* __restrict__ xh,
                    float* __restrict__ out)
{
  __shared__ short As[BM * LDKF];
  __shared__ short Bs[BN * LDKF];
  __shared__ float invA[BM];
  __shared__ float invB[BN];

  const int bid = blockIdx.x;
  const int b = bid >> 6, tile = bid & 63, tm = tile >> 3, tn = tile & 7;
  const float* Abase = xh  + (size_t)(b * Tt + tm * BM) * Dd;
  const float* Bbase = sup + (size_t)(b * Ss + tn * BN) * Dd;
  const int t = threadIdx.x, row = t >> 1, kh = t & 1;
  const f32x4* agp = (const f32x4*)(Abase + (size_t)row * Dd + kh * 16);
  const f32x4* bgp = (const f32x4*)(Bbase + (size_t)row * Dd + kh * 16);
  u32x4* awr = (u32x4*)(As + row * LDKF + kh * 16);
  u32x4* bwr = (u32x4*)(Bs + row * LDKF + kh * 16);
  const int wave = t >> 6, lane = t & 63;
  const int wm = (wave >> 1) << 6, wn = (wave & 1) << 6;
  const int lm = lane & 15, kq = lane >> 4;

  f32x4 acc[4][4];
  #pragma unroll
  for (int i = 0; i < 4; ++i)
    #pragma unroll
    for (int j = 0; j < 4; ++j) acc[i][j] = (f32x4)0.0f;
  float sqa = 0.0f, sqb = 0.0f;
  f32x4 areg[4], breg[4];
  #pragma unroll
  for (int i = 0; i < 4; ++i) { areg[i] = agp[i]; breg[i] = bgp[i]; }

  for (int k0 = 0; k0 < Dd; k0 += BKF) {
    unsigned pa[8], pb[8];
    #pragma unroll
    for (int i = 0; i < 4; ++i) {
      sqa = fmaf(areg[i][0], areg[i][0], sqa); sqa = fmaf(areg[i][1], areg[i][1], sqa);
      sqa = fmaf(areg[i][2], areg[i][2], sqa); sqa = fmaf(areg[i][3], areg[i][3], sqa);
      pa[i*2+0] = pack2_bf16(areg[i][0], areg[i][1]); pa[i*2+1] = pack2_bf16(areg[i][2], areg[i][3]);
      sqb = fmaf(breg[i][0], breg[i][0], sqb); sqb = fmaf(breg[i][1], breg[i][1], sqb);
      sqb = fmaf(breg[i][2], breg[i][2], sqb); sqb = fmaf(breg[i][3], breg[i][3], sqb);
      pb[i*2+0] = pack2_bf16(breg[i][0], breg[i][1]); pb[i*2+1] = pack2_bf16(breg[i][2], breg[i][3]);
    }
    __syncthreads();
    awr[0] = (u32x4){pa[0],pa[1],pa[2],pa[3]}; awr[1] = (u32x4){pa[4],pa[5],pa[6],pa[7]};
    bwr[0] = (u32x4){pb[0],pb[1],pb[2],pb[3]}; bwr[1] = (u32x4){pb[4],pb[5],pb[6],pb[7]};
    __syncthreads();
    if (k0 + BKF < Dd) {
      const int off = (k0 + BKF) >> 2;
      #pragma unroll
      for (int i = 0; i < 4; ++i) { areg[i] = agp[off + i]; breg[i] = bgp[off + i]; }
    }
    s16x8 af[4], bfr[4];
    #pragma unroll
    for (int i = 0; i < 4; ++i) {
      af[i]  = *(const s16x8*)(As + (wm + i*16 + lm) * LDKF + kq * 8);
      bfr[i] = *(const s16x8*)(Bs + (wn + i*16 + lm) * LDKF + kq * 8);
    }
    #pragma unroll
    for (int mi = 0; mi < 4; ++mi)
      #pragma unroll
      for (int ni = 0; ni < 4; ++ni)
        acc[mi][ni] = __builtin_amdgcn_mfma_f32_16x16x32_bf16(af[mi], bfr[ni], acc[mi][ni], 0, 0, 0);
  }
  __syncthreads();
  ((float*)As)[t] = sqa; ((float*)Bs)[t] = sqb;
  __syncthreads();
  if (t < 128) {
    invA[t] = 1.0f / sqrtf(((float*)As)[2*t] + ((float*)As)[2*t+1]);
    invB[t] = 1.0f / sqrtf(((float*)Bs)[2*t] + ((float*)Bs)[2*t+1]);
  }
  __syncthreads();
  float* outb = out + (size_t)(b * Tt + tm * BM) * Ss + tn * BN;
  const int m0 = wm + kq * 4, n0 = wn + lm;
  #pragma unroll
  for (int mi = 0; mi < 4; ++mi) {
    #pragma unroll
    for (int r = 0; r < 4; ++r) {
      const int mrow = m0 + mi * 16 + r;
      const float ia = invA[mrow];
      float* orow = outb + (size_t)mrow * Ss;
      #pragma unroll
      for (int ni = 0; ni < 4; ++ni) {
        const int ncol = n0 + ni * 16;
        orow[ncol] = acc[mi][ni][r] * (ia * invB[ncol]);
      }
    }
  }
}

extern "C" void kernel_launch(void* const* d_in, const int* in_sizes, int n_in,
                              void* d_out, int out_size, void* d_ws, size_t ws_size,
                              hipStream_t stream) {
  const float* sup = (const float*)d_in[0];  // support_sets [8,1024,2048]
  const float* xh  = (const float*)d_in[1];  // X_hats       [8,1024,2048]
  float* out = (float*)d_out;                // [8,1024,1024] fp32

  const size_t nElem = (size_t)Bb * Tt * Dd;              // 16.78M per tensor
  const size_t bfBytes = nElem * sizeof(short);           // 33.55 MB
  const size_t NEED = 2 * bfBytes + 2 * (size_t)Bb * Tt * sizeof(float);

  if (ws_size >= NEED) {
    unsigned* abf = (unsigned*)d_ws;
    unsigned* bbf = (unsigned*)((char*)d_ws + bfBytes);
    float* invA = (float*)((char*)d_ws + 2 * bfBytes);
    float* invB = invA + (size_t)Bb * Tt;
    convert_kernel<<<dim3(4096), dim3(256), 0, stream>>>(sup, xh, abf, bbf, invA, invB);
    gemm_kernel<<<dim3(512), dim3(256), 0, stream>>>((const short*)abf, (const short*)bbf,
                                                     invA, invB, out);
  } else {
    paircos_kernel<<<dim3(512), dim3(256), 0, stream>>>(sup, xh, out);
  }
}

// Round 6
// 205.146 us; speedup vs baseline: 1.0011x; 1.0011x over previous
//
#include <hip/hip_runtime.h>
#include <hip/hip_bf16.h>

typedef __attribute__((ext_vector_type(4))) float        f32x4;
typedef __attribute__((ext_vector_type(8))) short        s16x8;
typedef __attribute__((ext_vector_type(4))) unsigned int u32x4;

#define Bb 8
#define Tt 1024
#define Ss 1024
#define Dd 2048
#define BM 128
#define BN 128
#define BK 64   // K-slab per barrier: 32 iters, 32 MFMA/wave/iter

// round-half-up f32 -> bf16, packed pair. Inputs are finite N(0,1); no NaN/Inf path.
__device__ __forceinline__ unsigned pack2_bf16(float f0, float f1) {
  unsigned u0 = __builtin_bit_cast(unsigned, f0) + 0x8000u;
  unsigned u1 = __builtin_bit_cast(unsigned, f1) + 0x8000u;
  return (u0 >> 16) | (u1 & 0xffff0000u);
}

// async global->LDS DMA, 16B/lane. LDS dest = wave-uniform base + lane*16.
__device__ __forceinline__ void gld_lds16(const void* g, void* l) {
  __builtin_amdgcn_global_load_lds(
      (__attribute__((address_space(1))) void*)(void*)(g),
      (__attribute__((address_space(3))) void*)l, 16, 0, 0);
}

// ---------------- Pass 1: persistent, software-pipelined convert ----------------
// 1024 blocks x 4 waves; wave wgid handles rows {wgid, wgid+4096, wgid+8192, wgid+12288}
// (rowg < 8192 -> X_hats/A, else support/B). Next row's 8 loads issue before the
// current row's pack/store, so one HBM latency is exposed per wave, not four.
__device__ __forceinline__ const f32x4* cv_src(int rowg, const float* sup, const float* xh) {
  return (const f32x4*)(rowg < 8192 ? xh + (size_t)rowg * Dd
                                    : sup + (size_t)(rowg - 8192) * Dd);
}

__global__ __launch_bounds__(256, 4)
void convert_kernel(const float* __restrict__ sup, const float* __restrict__ xh,
                    unsigned* __restrict__ abf, unsigned* __restrict__ bbf,
                    float* __restrict__ invA, float* __restrict__ invB)
{
  const int wave = threadIdx.x >> 6, lane = threadIdx.x & 63;
  const int wgid = blockIdx.x * 4 + wave;   // 0..4095

  f32x4 buf[2][8];

  // prologue: load row wgid (lane owns 8 contiguous floats per 512-float segment)
  {
    const f32x4* sp = cv_src(wgid, sup, xh);
    #pragma unroll
    for (int j = 0; j < 4; ++j) {
      buf[0][2 * j]     = sp[j * 128 + lane * 2];
      buf[0][2 * j + 1] = sp[j * 128 + lane * 2 + 1];
    }
  }

  #pragma unroll
  for (int i = 0; i < 4; ++i) {
    const int rowg = wgid + i * 4096;

    // prefetch next row into the other buffer
    if (i < 3) {
      const f32x4* np = cv_src(rowg + 4096, sup, xh);
      #pragma unroll
      for (int j = 0; j < 4; ++j) {
        buf[(i + 1) & 1][2 * j]     = np[j * 128 + lane * 2];
        buf[(i + 1) & 1][2 * j + 1] = np[j * 128 + lane * 2 + 1];
      }
    }

    // process current row
    float sq = 0.0f;
    u32x4 o[4];
    #pragma unroll
    for (int j = 0; j < 4; ++j) {
      f32x4 a = buf[i & 1][2 * j], b = buf[i & 1][2 * j + 1];
      sq = fmaf(a[0], a[0], fmaf(a[1], a[1], fmaf(a[2], a[2], fmaf(a[3], a[3], sq))));
      sq = fmaf(b[0], b[0], fmaf(b[1], b[1], fmaf(b[2], b[2], fmaf(b[3], b[3], sq))));
      o[j] = (u32x4){pack2_bf16(a[0], a[1]), pack2_bf16(a[2], a[3]),
                     pack2_bf16(b[0], b[1]), pack2_bf16(b[2], b[3])};
    }

    unsigned* dst; float* inv; int row;
    if (rowg < 8192) { row = rowg;        dst = abf; inv = invA; }
    else             { row = rowg - 8192; dst = bbf; inv = invB; }
    u32x4* d = (u32x4*)(dst + (size_t)row * (Dd / 2));
    #pragma unroll
    for (int j = 0; j < 4; ++j) d[j * 64 + lane] = o[j];

    #pragma unroll
    for (int m = 32; m; m >>= 1) sq += __shfl_xor(sq, m, 64);
    if (lane == 0) inv[row] = 1.0f / sqrtf(sq);
  }
}

// ---------------- Pass 2: bf16 GEMM, DMA staging, BK=64 (unchanged control) ----------------
// LDS tiles 128x64 bf16 (128B rows, 8 chunks of 16B).
// XOR swizzle: LDS[r][p] = G[r][p ^ (r&7)]; read chunk c at p = c ^ (r&7).
__global__ __launch_bounds__(256, 2)
void gemm_kernel(const short* __restrict__ abf, const short* __restrict__ bbf,
                 const float* __restrict__ invA, const float* __restrict__ invB,
                 float* __restrict__ out)
{
  __shared__ short As[BM * BK];   // 16 KB
  __shared__ short Bs[BN * BK];   // 16 KB

  const int bid  = blockIdx.x;
  const int b    = bid >> 6;
  const int tile = bid & 63;
  const int tm   = tile >> 3;
  const int tn   = tile & 7;

  const int t = threadIdx.x, wave = t >> 6, lane = t & 63;

  // --- staging: wave covers rows [wave*32, wave*32+32), 4 DMA instrs per operand.
  const int srow = lane >> 3;
  const int cph  = lane & 7;
  const int r0   = wave * 32;

  const size_t aRow = (size_t)(b * Tt + tm * BM);
  const size_t bRow = (size_t)(b * Ss + tn * BN);
  const short *gA0, *gA1, *gA2, *gA3, *gB0, *gB1, *gB2, *gB3;
  {
    int r;
    r = r0 + 0 * 8 + srow; gA0 = abf + (aRow + r) * Dd + (cph ^ (r & 7)) * 8;
                           gB0 = bbf + (bRow + r) * Dd + (cph ^ (r & 7)) * 8;
    r = r0 + 1 * 8 + srow; gA1 = abf + (aRow + r) * Dd + (cph ^ (r & 7)) * 8;
                           gB1 = bbf + (bRow + r) * Dd + (cph ^ (r & 7)) * 8;
    r = r0 + 2 * 8 + srow; gA2 = abf + (aRow + r) * Dd + (cph ^ (r & 7)) * 8;
                           gB2 = bbf + (bRow + r) * Dd + (cph ^ (r & 7)) * 8;
    r = r0 + 3 * 8 + srow; gA3 = abf + (aRow + r) * Dd + (cph ^ (r & 7)) * 8;
                           gB3 = bbf + (bRow + r) * Dd + (cph ^ (r & 7)) * 8;
  }
  short* lA0 = As + (r0 + 0)  * BK;  // wave-uniform bases; HW adds lane*16B
  short* lA1 = As + (r0 + 8)  * BK;
  short* lA2 = As + (r0 + 16) * BK;
  short* lA3 = As + (r0 + 24) * BK;
  short* lB0 = Bs + (r0 + 0)  * BK;
  short* lB1 = Bs + (r0 + 8)  * BK;
  short* lB2 = Bs + (r0 + 16) * BK;
  short* lB3 = Bs + (r0 + 24) * BK;

  // --- compute setup
  const int wm = (wave >> 1) << 6;
  const int wn = (wave & 1) << 6;
  const int lm = lane & 15;
  const int kq = lane >> 4;

  f32x4 acc[4][4];
  #pragma unroll
  for (int i = 0; i < 4; ++i)
    #pragma unroll
    for (int j = 0; j < 4; ++j)
      acc[i][j] = (f32x4)0.0f;

  for (int k0 = 0; k0 < Dd; k0 += BK) {
    __syncthreads();                  // previous slab's frag reads done
    gld_lds16(gA0, lA0); gld_lds16(gA1, lA1); gld_lds16(gA2, lA2); gld_lds16(gA3, lA3);
    gld_lds16(gB0, lB0); gld_lds16(gB1, lB1); gld_lds16(gB2, lB2); gld_lds16(gB3, lB3);
    gA0 += BK; gA1 += BK; gA2 += BK; gA3 += BK;
    gB0 += BK; gB1 += BK; gB2 += BK; gB3 += BK;
    __syncthreads();                  // DMA landed

    #pragma unroll
    for (int ks = 0; ks < 2; ++ks) {
      const int pchunk = ((ks * 4 + kq) ^ (lm & 7)) * 8;   // swizzled 16B chunk, in shorts
      s16x8 af[4], bfr[4];
      #pragma unroll
      for (int i = 0; i < 4; ++i) {
        af[i]  = *(const s16x8*)(As + (wm + i * 16 + lm) * BK + pchunk);
        bfr[i] = *(const s16x8*)(Bs + (wn + i * 16 + lm) * BK + pchunk);
      }
      #pragma unroll
      for (int mi = 0; mi < 4; ++mi)
        #pragma unroll
        for (int ni = 0; ni < 4; ++ni)
          acc[mi][ni] = __builtin_amdgcn_mfma_f32_16x16x32_bf16(af[mi], bfr[ni], acc[mi][ni], 0, 0, 0);
    }
  }

  // --- epilogue: scale by 1/||x|| * 1/||s|| (eps guard vacuous: norms ~45)
  const float* iA = invA + b * Tt + tm * BM;
  const float* iB = invB + b * Ss + tn * BN;
  float* outb = out + (size_t)(b * Tt + tm * BM) * Ss + tn * BN;
  const int m0 = wm + kq * 4;
  const int n0 = wn + lm;
  #pragma unroll
  for (int mi = 0; mi < 4; ++mi) {
    #pragma unroll
    for (int r = 0; r < 4; ++r) {
      const int mrow = m0 + mi * 16 + r;
      const float ia = iA[mrow];
      float* orow = outb + (size_t)mrow * Ss;
      #pragma unroll
      for (int ni = 0; ni < 4; ++ni) {
        const int ncol = n0 + ni * 16;
        orow[ncol] = acc[mi][ni][r] * (ia * iB[ncol]);
      }
    }
  }
}

// ---------------- Fallback: round-1 fused kernel (used only if ws too small) ----------------
#define LDKF 40
#define BKF 32
__global__ __launch_bounds__(256, 2)
void paircos_kernel(const float* __restrict__ sup, const float* __restrict__ xh,
                    float* __restrict__ out)
{
  __shared__ short As[BM * LDKF];
  __shared__ short Bs[BN * LDKF];
  __shared__ float invA[BM];
  __shared__ float invB[BN];

  const int bid = blockIdx.x;
  const int b = bid >> 6, tile = bid & 63, tm = tile >> 3, tn = tile & 7;
  const float* Abase = xh  + (size_t)(b * Tt + tm * BM) * Dd;
  const float* Bbase = sup + (size_t)(b * Ss + tn * BN) * Dd;
  const int t = threadIdx.x, row = t >> 1, kh = t & 1;
  const f32x4* agp = (const f32x4*)(Abase + (size_t)row * Dd + kh * 16);
  const f32x4* bgp = (const f32x4*)(Bbase + (size_t)row * Dd + kh * 16);
  u32x4* awr = (u32x4*)(As + row * LDKF + kh * 16);
  u32x4* bwr = (u32x4*)(Bs + row * LDKF + kh * 16);
  const int wave = t >> 6, lane = t & 63;
  const int wm = (wave >> 1) << 6, wn = (wave & 1) << 6;
  const int lm = lane & 15, kq = lane >> 4;

  f32x4 acc[4][4];
  #pragma unroll
  for (int i = 0; i < 4; ++i)
    #pragma unroll
    for (int j = 0; j < 4; ++j) acc[i][j] = (f32x4)0.0f;
  float sqa = 0.0f, sqb = 0.0f;
  f32x4 areg[4], breg[4];
  #pragma unroll
  for (int i = 0; i < 4; ++i) { areg[i] = agp[i]; breg[i] = bgp[i]; }

  for (int k0 = 0; k0 < Dd; k0 += BKF) {
    unsigned pa[8], pb[8];
    #pragma unroll
    for (int i = 0; i < 4; ++i) {
      sqa = fmaf(areg[i][0], areg[i][0], sqa); sqa = fmaf(areg[i][1], areg[i][1], sqa);
      sqa = fmaf(areg[i][2], areg[i][2], sqa); sqa = fmaf(areg[i][3], areg[i][3], sqa);
      pa[i*2+0] = pack2_bf16(areg[i][0], areg[i][1]); pa[i*2+1] = pack2_bf16(areg[i][2], areg[i][3]);
      sqb = fmaf(breg[i][0], breg[i][0], sqb); sqb = fmaf(breg[i][1], breg[i][1], sqb);
      sqb = fmaf(breg[i][2], breg[i][2], sqb); sqb = fmaf(breg[i][3], breg[i][3], sqb);
      pb[i*2+0] = pack2_bf16(breg[i][0], breg[i][1]); pb[i*2+1] = pack2_bf16(breg[i][2], breg[i][3]);
    }
    __syncthreads();
    awr[0] = (u32x4){pa[0],pa[1],pa[2],pa[3]}; awr[1] = (u32x4){pa[4],pa[5],pa[6],pa[7]};
    bwr[0] = (u32x4){pb[0],pb[1],pb[2],pb[3]}; bwr[1] = (u32x4){pb[4],pb[5],pb[6],pb[7]};
    __syncthreads();
    if (k0 + BKF < Dd) {
      const int off = (k0 + BKF) >> 2;
      #pragma unroll
      for (int i = 0; i < 4; ++i) { areg[i] = agp[off + i]; breg[i] = bgp[off + i]; }
    }
    s16x8 af[4], bfr[4];
    #pragma unroll
    for (int i = 0; i < 4; ++i) {
      af[i]  = *(const s16x8*)(As + (wm + i*16 + lm) * LDKF + kq * 8);
      bfr[i] = *(const s16x8*)(Bs + (wn + i*16 + lm) * LDKF + kq * 8);
    }
    #pragma unroll
    for (int mi = 0; mi < 4; ++mi)
      #pragma unroll
      for (int ni = 0; ni < 4; ++ni)
        acc[mi][ni] = __builtin_amdgcn_mfma_f32_16x16x32_bf16(af[mi], bfr[ni], acc[mi][ni], 0, 0, 0);
  }
  __syncthreads();
  ((float*)As)[t] = sqa; ((float*)Bs)[t] = sqb;
  __syncthreads();
  if (t < 128) {
    invA[t] = 1.0f / sqrtf(((float*)As)[2*t] + ((float*)As)[2*t+1]);
    invB[t] = 1.0f / sqrtf(((float*)Bs)[2*t] + ((float*)Bs)[2*t+1]);
  }
  __syncthreads();
  float* outb = out + (size_t)(b * Tt + tm * BM) * Ss + tn * BN;
  const int m0 = wm + kq * 4, n0 = wn + lm;
  #pragma unroll
  for (int mi = 0; mi < 4; ++mi) {
    #pragma unroll
    for (int r = 0; r < 4; ++r) {
      const int mrow = m0 + mi * 16 + r;
      const float ia = invA[mrow];
      float* orow = outb + (size_t)mrow * Ss;
      #pragma unroll
      for (int ni = 0; ni < 4; ++ni) {
        const int ncol = n0 + ni * 16;
        orow[ncol] = acc[mi][ni][r] * (ia * invB[ncol]);
      }
    }
  }
}

extern "C" void kernel_launch(void* const* d_in, const int* in_sizes, int n_in,
                              void* d_out, int out_size, void* d_ws, size_t ws_size,
                              hipStream_t stream) {
  const float* sup = (const float*)d_in[0];  // support_sets [8,1024,2048]
  const float* xh  = (const float*)d_in[1];  // X_hats       [8,1024,2048]
  float* out = (float*)d_out;                // [8,1024,1024] fp32

  const size_t nElem = (size_t)Bb * Tt * Dd;              // 16.78M per tensor
  const size_t bfBytes = nElem * sizeof(short);           // 33.55 MB
  const size_t NEED = 2 * bfBytes + 2 * (size_t)Bb * Tt * sizeof(float);

  if (ws_size >= NEED) {
    unsigned* abf = (unsigned*)d_ws;
    unsigned* bbf = (unsigned*)((char*)d_ws + bfBytes);
    float* invA = (float*)((char*)d_ws + 2 * bfBytes);
    float* invB = invA + (size_t)Bb * Tt;
    convert_kernel<<<dim3(1024), dim3(256), 0, stream>>>(sup, xh, abf, bbf, invA, invB);
    gemm_kernel<<<dim3(512), dim3(256), 0, stream>>>((const short*)abf, (const short*)bbf,
                                                     invA, invB, out);
  } else {
    paircos_kernel<<<dim3(512), dim3(256), 0, stream>>>(sup, xh, out);
  }
}